// Round 1
// baseline (1334.859 us; speedup 1.0000x reference)
//
#include <hip/hip_runtime.h>
#include <hip/hip_bf16.h>
#include <math.h>

// ---------------- problem constants ----------------
#define BS   32
#define LQ   300
#define NQ   (BS*LQ)      // 9600
#define DMODEL 256
#define NH   8
#define DH   32
#define FF   1024
#define LV   8500
#define SP   16
#define TP   (NH*SP)      // 128

// ---------------- generic tiled GEMM:  Y[M,N] = op(A)[M,K] @ W[N,K]^T + bias ----------------
// ADD2: A := A + A2 (both [M,K])
// CONCAT: A := concat(A, A2) along K (each [M,K/2])
// RELU: relu epilogue
template<int ADD2, int CONCAT, int RELU>
__global__ __launch_bounds__(256) void gemm_xwt(
    const float* __restrict__ A, const float* __restrict__ A2,
    const float* __restrict__ W, const float* __restrict__ bias,
    float* __restrict__ Y, int M, int N, int K)
{
    __shared__ float As[16][65];
    __shared__ float Bs[16][65];
    const int m0 = blockIdx.x * 64;
    const int n0 = blockIdx.y * 64;
    const int tid = threadIdx.x;
    const int lm = tid >> 2;          // 0..63  (row within tile)
    const int lk = (tid & 3) * 4;     // 0,4,8,12
    const int tm = tid >> 4;          // 0..15
    const int tn = tid & 15;          // 0..15
    float acc[4][4] = {};
    for (int k0 = 0; k0 < K; k0 += 16) {
        float4 av;
        if constexpr (CONCAT) {
            const int kk = k0 + lk;
            const int Kh = K >> 1;
            if (kk < Kh) av = *(const float4*)&A [(size_t)(m0 + lm) * Kh + kk];
            else         av = *(const float4*)&A2[(size_t)(m0 + lm) * Kh + (kk - Kh)];
        } else {
            av = *(const float4*)&A[(size_t)(m0 + lm) * K + k0 + lk];
            if constexpr (ADD2) {
                float4 bv = *(const float4*)&A2[(size_t)(m0 + lm) * K + k0 + lk];
                av.x += bv.x; av.y += bv.y; av.z += bv.z; av.w += bv.w;
            }
        }
        As[lk + 0][lm] = av.x; As[lk + 1][lm] = av.y;
        As[lk + 2][lm] = av.z; As[lk + 3][lm] = av.w;
        float4 wv = *(const float4*)&W[(size_t)(n0 + lm) * K + k0 + lk];
        Bs[lk + 0][lm] = wv.x; Bs[lk + 1][lm] = wv.y;
        Bs[lk + 2][lm] = wv.z; Bs[lk + 3][lm] = wv.w;
        __syncthreads();
        #pragma unroll
        for (int kk = 0; kk < 16; ++kk) {
            float a[4], b[4];
            #pragma unroll
            for (int i = 0; i < 4; ++i) a[i] = As[kk][tm * 4 + i];
            #pragma unroll
            for (int j = 0; j < 4; ++j) b[j] = Bs[kk][tn * 4 + j];
            #pragma unroll
            for (int i = 0; i < 4; ++i)
                #pragma unroll
                for (int j = 0; j < 4; ++j)
                    acc[i][j] += a[i] * b[j];
        }
        __syncthreads();
    }
    #pragma unroll
    for (int i = 0; i < 4; ++i) {
        const int m = m0 + tm * 4 + i;
        #pragma unroll
        for (int j = 0; j < 4; ++j) {
            const int n = n0 + tn * 4 + j;
            float v = acc[i][j] + bias[n];
            if constexpr (RELU) v = fmaxf(v, 0.f);
            Y[(size_t)m * N + n] = v;
        }
    }
}

// ---------------- self-attention core: per (b,h) block ----------------
// qh/kh/vh in [NQ, DMODEL] layout, channel = h*DH + d
__global__ __launch_bounds__(256) void attn_kernel(
    const float* __restrict__ qh, const float* __restrict__ kh,
    const float* __restrict__ vh, float* __restrict__ out)
{
    const int b = blockIdx.x >> 3;
    const int h = blockIdx.x & 7;
    __shared__ float Ksh[LQ][DH + 1];
    __shared__ float Vsh[LQ][DH + 1];
    __shared__ float Psh[4][LQ + 4];
    const int tid = threadIdx.x;
    for (int idx = tid; idx < LQ * DH; idx += 256) {
        const int l = idx >> 5, d = idx & 31;
        const size_t g = ((size_t)(b * LQ + l)) * DMODEL + h * DH + d;
        Ksh[l][d] = kh[g];
        Vsh[l][d] = vh[g];
    }
    __syncthreads();
    const int w = tid >> 6;
    const int lane = tid & 63;
    const float scale = 0.17677669529663687f; // 1/sqrt(32)
    for (int qi = w; qi < LQ; qi += 4) {      // 75 iters for every wave
        float qv[DH];
        const float* qp = &qh[((size_t)(b * LQ + qi)) * DMODEL + h * DH];
        #pragma unroll
        for (int d = 0; d < DH; ++d) qv[d] = qp[d];
        float s[5];
        #pragma unroll
        for (int i = 0; i < 5; ++i) {
            const int k = lane + i * 64;
            if (k < LQ) {
                float acc = 0.f;
                #pragma unroll
                for (int d = 0; d < DH; ++d) acc += qv[d] * Ksh[k][d];
                s[i] = acc * scale;
            } else s[i] = -1e30f;
        }
        float mx = s[0];
        #pragma unroll
        for (int i = 1; i < 5; ++i) mx = fmaxf(mx, s[i]);
        #pragma unroll
        for (int off = 32; off >= 1; off >>= 1) mx = fmaxf(mx, __shfl_xor(mx, off, 64));
        float sum = 0.f;
        #pragma unroll
        for (int i = 0; i < 5; ++i) { s[i] = expf(s[i] - mx); sum += s[i]; }
        #pragma unroll
        for (int off = 32; off >= 1; off >>= 1) sum += __shfl_xor(sum, off, 64);
        const float inv = 1.f / sum;
        #pragma unroll
        for (int i = 0; i < 5; ++i) {
            const int k = lane + i * 64;
            if (k < LQ) Psh[w][k] = s[i] * inv;
        }
        __syncthreads();  // all waves execute 75 iterations -> aligned
        const int d = lane & 31, half = lane >> 5;
        float o = 0.f;
        const int kb = half * 150;
        for (int k = kb; k < kb + 150; ++k)
            o += Psh[w][k] * Vsh[k][d];
        o += __shfl_xor(o, 32, 64);
        if (half == 0)
            out[((size_t)(b * LQ + qi)) * DMODEL + h * DH + d] = o;
        __syncthreads();
    }
}

// ---------------- row reductions / LayerNorm helpers ----------------
__device__ __forceinline__ float row_reduce_256(float v, float* red) {
    #pragma unroll
    for (int off = 32; off >= 1; off >>= 1) v += __shfl_xor(v, off, 64);
    const int tid = threadIdx.x;
    if ((tid & 63) == 0) red[tid >> 6] = v;
    __syncthreads();
    v = red[0] + red[1] + red[2] + red[3];
    __syncthreads();
    return v;
}

__device__ __forceinline__ void ln_store(float v, const float* __restrict__ g,
                                         const float* __restrict__ be,
                                         float* __restrict__ y, size_t row, int tid, float* red)
{
    const float mean = row_reduce_256(v, red) * (1.f / 256.f);
    const float dv = v - mean;
    const float var = row_reduce_256(dv * dv, red) * (1.f / 256.f);
    const float r = rsqrtf(var + 1e-5f);
    y[row * DMODEL + tid] = dv * r * g[tid] + be[tid];
}

// t = LN(res + x)
__global__ __launch_bounds__(256) void ln_add_kernel(
    const float* __restrict__ res, const float* __restrict__ x,
    const float* __restrict__ g, const float* __restrict__ be, float* __restrict__ y)
{
    __shared__ float red[4];
    const size_t row = blockIdx.x;
    const int tid = threadIdx.x;
    const float v = res[row * DMODEL + tid] + x[row * DMODEL + tid];
    ln_store(v, g, be, y, row, tid, red);
}

// t = LN(sigmoid(gl[:256])*t + sigmoid(gl[256:])*t2)
__global__ __launch_bounds__(256) void gate_ln_kernel(
    const float* __restrict__ gl, const float* __restrict__ t,
    const float* __restrict__ t2, const float* __restrict__ g,
    const float* __restrict__ be, float* __restrict__ y)
{
    __shared__ float red[4];
    const size_t row = blockIdx.x;
    const int tid = threadIdx.x;
    const float ga = 1.f / (1.f + expf(-gl[row * 512 + tid]));
    const float gb = 1.f / (1.f + expf(-gl[row * 512 + 256 + tid]));
    const float v = ga * t[row * DMODEL + tid] + gb * t2[row * DMODEL + tid];
    ln_store(v, g, be, y, row, tid, red);
}

// out = LN(clip(t + x))
__global__ __launch_bounds__(256) void ln_final_kernel(
    const float* __restrict__ t, const float* __restrict__ x,
    const float* __restrict__ g, const float* __restrict__ be, float* __restrict__ y)
{
    __shared__ float red[4];
    const size_t row = blockIdx.x;
    const int tid = threadIdx.x;
    float v = t[row * DMODEL + tid] + x[row * DMODEL + tid];
    v = fminf(fmaxf(v, -65504.f), 65504.f);
    ln_store(v, g, be, y, row, tid, red);
}

// ---------------- sampling prep: softmax(aw) + sampling locations ----------------
__global__ __launch_bounds__(128) void prep_kernel(
    const float* __restrict__ so, const float* __restrict__ awl,
    const float* __restrict__ refp, float* __restrict__ loc, float* __restrict__ aw)
{
    const size_t bq = blockIdx.x;
    const int tid = threadIdx.x;   // h*16 + p
    const float4 rp = *(const float4*)&refp[bq * 4];
    const float l = awl[bq * TP + tid];
    float mx = l;
    #pragma unroll
    for (int off = 1; off < 16; off <<= 1) mx = fmaxf(mx, __shfl_xor(mx, off, 16));
    const float e = expf(l - mx);
    float sum = e;
    #pragma unroll
    for (int off = 1; off < 16; off <<= 1) sum += __shfl_xor(sum, off, 16);
    aw[bq * TP + tid] = e / sum;
    const float sx = so[bq * 256 + tid * 2 + 0];
    const float sy = so[bq * 256 + tid * 2 + 1];
    const float npsc = 0.25f, osc = 0.5f;
    loc[(bq * TP + tid) * 2 + 0] = rp.x + sx * npsc * rp.z * osc;
    loc[(bq * TP + tid) * 2 + 1] = rp.y + sy * npsc * rp.w * osc;
}

// ---------------- MS deformable sampling ----------------
__global__ __launch_bounds__(256) void deform_kernel(
    const float* __restrict__ value, const float* __restrict__ loc,
    const float* __restrict__ aw, float* __restrict__ t2)
{
    __shared__ float Lloc[2 * TP];
    __shared__ float Law[TP];
    const size_t bq = blockIdx.x;
    const int b = (int)(bq / LQ);
    const int tid = threadIdx.x;
    Lloc[tid] = loc[bq * 2 * TP + tid];
    if (tid < TP) Law[tid] = aw[bq * TP + tid];
    __syncthreads();
    const int h = tid >> 5, d = tid & 31;
    const float* vbase = value + (size_t)b * LV * DMODEL + h * DH + d;
    float acc = 0.f;
    #pragma unroll
    for (int p = 0; p < SP; ++p) {
        const int lvl = p >> 2;
        const int HW  = (lvl == 0) ? 80 : (lvl == 1) ? 40 : (lvl == 2) ? 20 : 10;
        const int st  = (lvl == 0) ? 0  : (lvl == 1) ? 6400 : (lvl == 2) ? 8000 : 8400;
        const float lx = Lloc[(h * SP + p) * 2 + 0] * HW - 0.5f;
        const float ly = Lloc[(h * SP + p) * 2 + 1] * HW - 0.5f;
        const float x0f = floorf(lx), y0f = floorf(ly);
        const float dx = lx - x0f, dy = ly - y0f;
        const int x0 = (int)x0f, y0 = (int)y0f;
        const float a = Law[h * SP + p];
        const float w00 = (1.f - dy) * (1.f - dx) * a;
        const float w01 = (1.f - dy) * dx * a;
        const float w10 = dy * (1.f - dx) * a;
        const float w11 = dy * dx * a;
        const bool xv0 = (x0 >= 0) & (x0 < HW);
        const bool xv1 = (x0 + 1 >= 0) & (x0 + 1 < HW);
        if (y0 >= 0 && y0 < HW) {
            const float* r = vbase + (size_t)(st + y0 * HW) * DMODEL;
            if (xv0) acc += w00 * r[(size_t)x0 * DMODEL];
            if (xv1) acc += w01 * r[(size_t)(x0 + 1) * DMODEL];
        }
        if (y0 + 1 >= 0 && y0 + 1 < HW) {
            const float* r = vbase + (size_t)(st + (y0 + 1) * HW) * DMODEL;
            if (xv0) acc += w10 * r[(size_t)x0 * DMODEL];
            if (xv1) acc += w11 * r[(size_t)(x0 + 1) * DMODEL];
        }
    }
    t2[bq * DMODEL + tid] = acc;
}

// ---------------- launcher ----------------
extern "C" void kernel_launch(void* const* d_in, const int* in_sizes, int n_in,
                              void* d_out, int out_size, void* d_ws, size_t ws_size,
                              hipStream_t stream) {
    const float* target = (const float*)d_in[0];
    const float* refp   = (const float*)d_in[1];
    const float* value  = (const float*)d_in[2];
    const float* qpe    = (const float*)d_in[3];
    const float* Wq = (const float*)d_in[4];  const float* bq = (const float*)d_in[5];
    const float* Wk = (const float*)d_in[6];  const float* bk = (const float*)d_in[7];
    const float* Wv = (const float*)d_in[8];  const float* bv = (const float*)d_in[9];
    const float* Wo = (const float*)d_in[10]; const float* bo = (const float*)d_in[11];
    const float* g1 = (const float*)d_in[12]; const float* be1 = (const float*)d_in[13];
    const float* so_W = (const float*)d_in[14]; const float* so_b = (const float*)d_in[15];
    const float* aw_W = (const float*)d_in[16]; const float* aw_b = (const float*)d_in[17];
    const float* gate_W = (const float*)d_in[18]; const float* gate_b = (const float*)d_in[19];
    const float* g2 = (const float*)d_in[20]; const float* be2 = (const float*)d_in[21];
    const float* l1_W = (const float*)d_in[22]; const float* l1_b = (const float*)d_in[23];
    const float* l2_W = (const float*)d_in[24]; const float* l2_b = (const float*)d_in[25];
    const float* g3 = (const float*)d_in[26]; const float* be3 = (const float*)d_in[27];

    float* ws = (float*)d_ws;
    const size_t S1 = (size_t)NQ * DMODEL;      // 2,457,600 floats
    float* w0 = ws;            // qh -> oproj -> ffn_out
    float* w1 = ws + 1 * S1;   // kh -> aw_logits | aw
    float* w2 = ws + 2 * S1;   // vh -> so_out -> tf
    float* w3 = ws + 3 * S1;   // attn_out -> loc
    float* w4 = ws + 4 * S1;   // t2
    float* w5 = ws + 5 * S1;   // t
    float* w6 = ws + 6 * S1;   // glogits (2*S1)
    float* w7 = ws + 8 * S1;   // ffn hidden (4*S1)
    float* aw_buf = w1 + (size_t)NQ * TP;       // second half of w1

    const dim3 blk(256);
    // --- self attention ---
    gemm_xwt<1,0,0><<<dim3(NQ/64, 4), blk, 0, stream>>>(target, qpe, Wq, bq, w0, NQ, 256, 256);
    gemm_xwt<1,0,0><<<dim3(NQ/64, 4), blk, 0, stream>>>(target, qpe, Wk, bk, w1, NQ, 256, 256);
    gemm_xwt<0,0,0><<<dim3(NQ/64, 4), blk, 0, stream>>>(target, nullptr, Wv, bv, w2, NQ, 256, 256);
    attn_kernel<<<BS * NH, blk, 0, stream>>>(w0, w1, w2, w3);
    gemm_xwt<0,0,0><<<dim3(NQ/64, 4), blk, 0, stream>>>(w3, nullptr, Wo, bo, w0, NQ, 256, 256);
    ln_add_kernel<<<NQ, blk, 0, stream>>>(target, w0, g1, be1, w5);
    // --- deformable cross attention ---
    gemm_xwt<1,0,0><<<dim3(NQ/64, 4), blk, 0, stream>>>(w5, qpe, so_W, so_b, w2, NQ, 256, 256);
    gemm_xwt<1,0,0><<<dim3(NQ/64, 2), blk, 0, stream>>>(w5, qpe, aw_W, aw_b, w1, NQ, 128, 256);
    prep_kernel<<<NQ, dim3(128), 0, stream>>>(w2, w1, refp, w3, aw_buf);
    deform_kernel<<<NQ, blk, 0, stream>>>(value, w3, aw_buf, w4);
    // --- gated fusion ---
    gemm_xwt<0,1,0><<<dim3(NQ/64, 8), blk, 0, stream>>>(w5, w4, gate_W, gate_b, w6, NQ, 512, 512);
    gate_ln_kernel<<<NQ, blk, 0, stream>>>(w6, w5, w4, g2, be2, w2);
    // --- FFN ---
    gemm_xwt<0,0,1><<<dim3(NQ/64, 16), blk, 0, stream>>>(w2, nullptr, l1_W, l1_b, w7, NQ, 1024, 256);
    gemm_xwt<0,0,0><<<dim3(NQ/64, 4), blk, 0, stream>>>(w7, nullptr, l2_W, l2_b, w0, NQ, 256, 1024);
    ln_final_kernel<<<NQ, blk, 0, stream>>>(w2, w0, g3, be3, (float*)d_out);
}

// Round 2
// 913.974 us; speedup vs baseline: 1.4605x; 1.4605x over previous
//
#include <hip/hip_runtime.h>
#include <hip/hip_bf16.h>
#include <math.h>

// ---------------- problem constants ----------------
#define BS   32
#define LQ   300
#define NQ   (BS*LQ)      // 9600
#define DMODEL 256
#define NH   8
#define DH   32
#define FF   1024
#define LV   8500
#define SP   16
#define TP   (NH*SP)      // 128

typedef __attribute__((ext_vector_type(8))) short s8b;    // 8 bf16 (4 VGPRs)
typedef __attribute__((ext_vector_type(4))) float f32x4;  // MFMA acc

__device__ __forceinline__ unsigned short f2bf(float f) {
    __hip_bfloat16 h = __float2bfloat16(f);
    return *reinterpret_cast<unsigned short*>(&h);
}

// ---------------- weight fp32 -> bf16 conversion ----------------
struct CvtArgs {
    const float* src[9];
    unsigned short* dst[9];
    int n[9];
};

__global__ __launch_bounds__(256) void cvt_weights(CvtArgs a) {
    const int wi = blockIdx.y;
    const int idx = (blockIdx.x * 256 + threadIdx.x) * 4;
    if (idx >= a.n[wi]) return;
    const float4 v = *(const float4*)&a.src[wi][idx];
    ushort4 u;
    u.x = f2bf(v.x); u.y = f2bf(v.y); u.z = f2bf(v.z); u.w = f2bf(v.w);
    *(ushort4*)&a.dst[wi][idx] = u;
}

// ---------------- bf16 MFMA GEMM:  Y[M,N] = op(A)[M,K] @ W[N,K]^T + bias ----------------
// A fp32 (converted to bf16 while staging); W bf16 pre-converted.
// ADD2: A := A + A2; CONCAT: A := concat(A,A2) along K; RELU epilogue.
// Tile 64x64, BK=32, 256 threads (4 waves, wave w owns 16 output cols).
template<int ADD2, int CONCAT, int RELU>
__global__ __launch_bounds__(256) void gemm_mfma(
    const float* __restrict__ A, const float* __restrict__ A2,
    const unsigned short* __restrict__ Wb, const float* __restrict__ bias,
    float* __restrict__ Y, int M, int N, int K)
{
    __shared__ __align__(16) unsigned short As[64][32];
    __shared__ __align__(16) unsigned short Bs[64][32];
    const int m0 = blockIdx.x * 64;
    const int n0 = blockIdx.y * 64;
    const int tid = threadIdx.x;
    // A staging: 8 lanes per row (128B contiguous global), 2 row-passes
    const int arow = tid >> 3;       // 0..31
    const int af4  = tid & 7;        // float4 index (k = af4*4)
    // B staging: 4 lanes per row, 16B (8 bf16) each
    const int brow = tid >> 2;       // 0..63
    const int b8   = tid & 3;        // k = b8*8
    // fragment indices
    const int wq   = tid >> 6;       // wave 0..3 -> n-strip
    const int lane = tid & 63;
    const int lr   = lane & 15;
    const int lg   = lane >> 4;

    f32x4 acc[4];
    #pragma unroll
    for (int mc = 0; mc < 4; ++mc) acc[mc] = (f32x4){0.f, 0.f, 0.f, 0.f};

    for (int k0 = 0; k0 < K; k0 += 32) {
        // ---- stage A (fp32 -> bf16) ----
        #pragma unroll
        for (int p = 0; p < 2; ++p) {
            const int row = arow + p * 32;
            const int gk = k0 + af4 * 4;
            float4 av;
            if constexpr (CONCAT) {
                const int Kh = K >> 1;
                if (gk < Kh) av = *(const float4*)&A [(size_t)(m0 + row) * Kh + gk];
                else         av = *(const float4*)&A2[(size_t)(m0 + row) * Kh + (gk - Kh)];
            } else {
                av = *(const float4*)&A[(size_t)(m0 + row) * K + gk];
                if constexpr (ADD2) {
                    const float4 bv = *(const float4*)&A2[(size_t)(m0 + row) * K + gk];
                    av.x += bv.x; av.y += bv.y; av.z += bv.z; av.w += bv.w;
                }
            }
            ushort4 u;
            u.x = f2bf(av.x); u.y = f2bf(av.y); u.z = f2bf(av.z); u.w = f2bf(av.w);
            *(ushort4*)&As[row][af4 * 4] = u;
        }
        // ---- stage B (bf16 direct) ----
        {
            const s8b wv = *(const s8b*)&Wb[(size_t)(n0 + brow) * K + k0 + b8 * 8];
            *(s8b*)&Bs[brow][b8 * 8] = wv;
        }
        __syncthreads();
        // ---- MFMA ----
        const s8b bfrag = *(const s8b*)&Bs[16 * wq + lr][8 * lg];
        #pragma unroll
        for (int mc = 0; mc < 4; ++mc) {
            const s8b afrag = *(const s8b*)&As[16 * mc + lr][8 * lg];
            acc[mc] = __builtin_amdgcn_mfma_f32_16x16x32_bf16(afrag, bfrag, acc[mc], 0, 0, 0);
        }
        __syncthreads();
    }
    // ---- epilogue: C/D layout col=lane&15, row=(lane>>4)*4+reg ----
    const int col = n0 + 16 * wq + lr;
    const float bv = bias[col];
    #pragma unroll
    for (int mc = 0; mc < 4; ++mc) {
        #pragma unroll
        for (int r = 0; r < 4; ++r) {
            const int row = m0 + 16 * mc + 4 * lg + r;
            float v = acc[mc][r] + bv;
            if constexpr (RELU) v = fmaxf(v, 0.f);
            Y[(size_t)row * N + col] = v;
        }
    }
}

// ---------------- self-attention core: per (b,h) block, 8 waves ----------------
__global__ __launch_bounds__(512) void attn_kernel(
    const float* __restrict__ qh, const float* __restrict__ kh,
    const float* __restrict__ vh, float* __restrict__ out)
{
    const int b = blockIdx.x >> 3;
    const int h = blockIdx.x & 7;
    __shared__ float Ksh[LQ][DH + 1];
    __shared__ float Vsh[LQ][DH + 1];
    __shared__ float Psh[8][LQ + 4];
    const int tid = threadIdx.x;
    for (int idx = tid; idx < LQ * DH; idx += 512) {
        const int l = idx >> 5, d = idx & 31;
        const size_t g = ((size_t)(b * LQ + l)) * DMODEL + h * DH + d;
        Ksh[l][d] = kh[g];
        Vsh[l][d] = vh[g];
    }
    __syncthreads();
    const int w = tid >> 6;       // 0..7
    const int lane = tid & 63;
    const float scale = 0.17677669529663687f; // 1/sqrt(32)
    for (int it = 0; it < 38; ++it) {         // 38*8 = 304 >= 300, uniform for barriers
        const int qi = it * 8 + w;
        const bool act = qi < LQ;
        float qv[DH];
        if (act) {
            const float* qp = &qh[((size_t)(b * LQ + qi)) * DMODEL + h * DH];
            #pragma unroll
            for (int d = 0; d < DH; ++d) qv[d] = qp[d];
        } else {
            #pragma unroll
            for (int d = 0; d < DH; ++d) qv[d] = 0.f;
        }
        float s[5];
        #pragma unroll
        for (int i = 0; i < 5; ++i) {
            const int k = lane + i * 64;
            if (k < LQ) {
                float acc = 0.f;
                #pragma unroll
                for (int d = 0; d < DH; ++d) acc += qv[d] * Ksh[k][d];
                s[i] = acc * scale;
            } else s[i] = -1e30f;
        }
        float mx = s[0];
        #pragma unroll
        for (int i = 1; i < 5; ++i) mx = fmaxf(mx, s[i]);
        #pragma unroll
        for (int off = 32; off >= 1; off >>= 1) mx = fmaxf(mx, __shfl_xor(mx, off, 64));
        float sum = 0.f;
        #pragma unroll
        for (int i = 0; i < 5; ++i) { s[i] = expf(s[i] - mx); sum += s[i]; }
        #pragma unroll
        for (int off = 32; off >= 1; off >>= 1) sum += __shfl_xor(sum, off, 64);
        const float inv = 1.f / sum;
        if (act) {
            #pragma unroll
            for (int i = 0; i < 5; ++i) {
                const int k = lane + i * 64;
                if (k < LQ) Psh[w][k] = s[i] * inv;
            }
        }
        __syncthreads();
        if (act) {
            const int d = lane & 31, half = lane >> 5;
            float o = 0.f;
            const int kb = half * 150;
            for (int k = kb; k < kb + 150; ++k)
                o += Psh[w][k] * Vsh[k][d];
            o += __shfl_xor(o, 32, 64);
            if (half == 0)
                out[((size_t)(b * LQ + qi)) * DMODEL + h * DH + d] = o;
        }
        __syncthreads();
    }
}

// ---------------- row reductions / LayerNorm helpers ----------------
__device__ __forceinline__ float row_reduce_256(float v, float* red) {
    #pragma unroll
    for (int off = 32; off >= 1; off >>= 1) v += __shfl_xor(v, off, 64);
    const int tid = threadIdx.x;
    if ((tid & 63) == 0) red[tid >> 6] = v;
    __syncthreads();
    v = red[0] + red[1] + red[2] + red[3];
    __syncthreads();
    return v;
}

__device__ __forceinline__ void ln_store(float v, const float* __restrict__ g,
                                         const float* __restrict__ be,
                                         float* __restrict__ y, size_t row, int tid, float* red)
{
    const float mean = row_reduce_256(v, red) * (1.f / 256.f);
    const float dv = v - mean;
    const float var = row_reduce_256(dv * dv, red) * (1.f / 256.f);
    const float r = rsqrtf(var + 1e-5f);
    y[row * DMODEL + tid] = dv * r * g[tid] + be[tid];
}

__global__ __launch_bounds__(256) void ln_add_kernel(
    const float* __restrict__ res, const float* __restrict__ x,
    const float* __restrict__ g, const float* __restrict__ be, float* __restrict__ y)
{
    __shared__ float red[4];
    const size_t row = blockIdx.x;
    const int tid = threadIdx.x;
    const float v = res[row * DMODEL + tid] + x[row * DMODEL + tid];
    ln_store(v, g, be, y, row, tid, red);
}

__global__ __launch_bounds__(256) void gate_ln_kernel(
    const float* __restrict__ gl, const float* __restrict__ t,
    const float* __restrict__ t2, const float* __restrict__ g,
    const float* __restrict__ be, float* __restrict__ y)
{
    __shared__ float red[4];
    const size_t row = blockIdx.x;
    const int tid = threadIdx.x;
    const float ga = 1.f / (1.f + expf(-gl[row * 512 + tid]));
    const float gb = 1.f / (1.f + expf(-gl[row * 512 + 256 + tid]));
    const float v = ga * t[row * DMODEL + tid] + gb * t2[row * DMODEL + tid];
    ln_store(v, g, be, y, row, tid, red);
}

__global__ __launch_bounds__(256) void ln_final_kernel(
    const float* __restrict__ t, const float* __restrict__ x,
    const float* __restrict__ g, const float* __restrict__ be, float* __restrict__ y)
{
    __shared__ float red[4];
    const size_t row = blockIdx.x;
    const int tid = threadIdx.x;
    float v = t[row * DMODEL + tid] + x[row * DMODEL + tid];
    v = fminf(fmaxf(v, -65504.f), 65504.f);
    ln_store(v, g, be, y, row, tid, red);
}

// ---------------- sampling prep: softmax(aw) + sampling locations ----------------
__global__ __launch_bounds__(128) void prep_kernel(
    const float* __restrict__ so, const float* __restrict__ awl,
    const float* __restrict__ refp, float* __restrict__ loc, float* __restrict__ aw)
{
    const size_t bq = blockIdx.x;
    const int tid = threadIdx.x;   // h*16 + p
    const float4 rp = *(const float4*)&refp[bq * 4];
    const float l = awl[bq * TP + tid];
    float mx = l;
    #pragma unroll
    for (int off = 1; off < 16; off <<= 1) mx = fmaxf(mx, __shfl_xor(mx, off, 16));
    const float e = expf(l - mx);
    float sum = e;
    #pragma unroll
    for (int off = 1; off < 16; off <<= 1) sum += __shfl_xor(sum, off, 16);
    aw[bq * TP + tid] = e / sum;
    const float sx = so[bq * 256 + tid * 2 + 0];
    const float sy = so[bq * 256 + tid * 2 + 1];
    const float npsc = 0.25f, osc = 0.5f;
    loc[(bq * TP + tid) * 2 + 0] = rp.x + sx * npsc * rp.z * osc;
    loc[(bq * TP + tid) * 2 + 1] = rp.y + sy * npsc * rp.w * osc;
}

// ---------------- MS deformable sampling ----------------
__global__ __launch_bounds__(256) void deform_kernel(
    const float* __restrict__ value, const float* __restrict__ loc,
    const float* __restrict__ aw, float* __restrict__ t2)
{
    __shared__ float Lloc[2 * TP];
    __shared__ float Law[TP];
    const size_t bq = blockIdx.x;
    const int b = (int)(bq / LQ);
    const int tid = threadIdx.x;
    Lloc[tid] = loc[bq * 2 * TP + tid];
    if (tid < TP) Law[tid] = aw[bq * TP + tid];
    __syncthreads();
    const int h = tid >> 5, d = tid & 31;
    const float* vbase = value + (size_t)b * LV * DMODEL + h * DH + d;
    float acc = 0.f;
    #pragma unroll
    for (int p = 0; p < SP; ++p) {
        const int lvl = p >> 2;
        const int HW  = (lvl == 0) ? 80 : (lvl == 1) ? 40 : (lvl == 2) ? 20 : 10;
        const int st  = (lvl == 0) ? 0  : (lvl == 1) ? 6400 : (lvl == 2) ? 8000 : 8400;
        const float lx = Lloc[(h * SP + p) * 2 + 0] * HW - 0.5f;
        const float ly = Lloc[(h * SP + p) * 2 + 1] * HW - 0.5f;
        const float x0f = floorf(lx), y0f = floorf(ly);
        const float dx = lx - x0f, dy = ly - y0f;
        const int x0 = (int)x0f, y0 = (int)y0f;
        const float a = Law[h * SP + p];
        const float w00 = (1.f - dy) * (1.f - dx) * a;
        const float w01 = (1.f - dy) * dx * a;
        const float w10 = dy * (1.f - dx) * a;
        const float w11 = dy * dx * a;
        const bool xv0 = (x0 >= 0) & (x0 < HW);
        const bool xv1 = (x0 + 1 >= 0) & (x0 + 1 < HW);
        if (y0 >= 0 && y0 < HW) {
            const float* r = vbase + (size_t)(st + y0 * HW) * DMODEL;
            if (xv0) acc += w00 * r[(size_t)x0 * DMODEL];
            if (xv1) acc += w01 * r[(size_t)(x0 + 1) * DMODEL];
        }
        if (y0 + 1 >= 0 && y0 + 1 < HW) {
            const float* r = vbase + (size_t)(st + (y0 + 1) * HW) * DMODEL;
            if (xv0) acc += w10 * r[(size_t)x0 * DMODEL];
            if (xv1) acc += w11 * r[(size_t)(x0 + 1) * DMODEL];
        }
    }
    t2[bq * DMODEL + tid] = acc;
}

// ---------------- launcher ----------------
extern "C" void kernel_launch(void* const* d_in, const int* in_sizes, int n_in,
                              void* d_out, int out_size, void* d_ws, size_t ws_size,
                              hipStream_t stream) {
    const float* target = (const float*)d_in[0];
    const float* refp   = (const float*)d_in[1];
    const float* value  = (const float*)d_in[2];
    const float* qpe    = (const float*)d_in[3];
    const float* Wq = (const float*)d_in[4];  const float* bq = (const float*)d_in[5];
    const float* Wk = (const float*)d_in[6];  const float* bk = (const float*)d_in[7];
    const float* Wv = (const float*)d_in[8];  const float* bv = (const float*)d_in[9];
    const float* Wo = (const float*)d_in[10]; const float* bo = (const float*)d_in[11];
    const float* g1 = (const float*)d_in[12]; const float* be1 = (const float*)d_in[13];
    const float* so_W = (const float*)d_in[14]; const float* so_b = (const float*)d_in[15];
    const float* aw_W = (const float*)d_in[16]; const float* aw_b = (const float*)d_in[17];
    const float* gate_W = (const float*)d_in[18]; const float* gate_b = (const float*)d_in[19];
    const float* g2 = (const float*)d_in[20]; const float* be2 = (const float*)d_in[21];
    const float* l1_W = (const float*)d_in[22]; const float* l1_b = (const float*)d_in[23];
    const float* l2_W = (const float*)d_in[24]; const float* l2_b = (const float*)d_in[25];
    const float* g3 = (const float*)d_in[26]; const float* be3 = (const float*)d_in[27];

    float* ws = (float*)d_ws;
    const size_t S1 = (size_t)NQ * DMODEL;      // 2,457,600 floats
    float* b0 = ws;            // qh -> oproj out -> ffn out
    float* b1 = ws + 1 * S1;   // kh -> aw logits (+aw softmax at offset)
    float* b2 = ws + 2 * S1;   // vh -> so out -> tf
    float* b3 = ws + 3 * S1;   // attn out -> loc -> ffn hidden (4*S1: 3S1..7S1)
    float* b4 = ws + 4 * S1;   // t2 (deform out)
    float* b5 = ws + 5 * S1;   // t
    float* b6 = ws + 6 * S1;   // gate logits (2*S1)
    float* aw_buf = b1 + (size_t)NQ * TP;

    // bf16 weights at ws + 8*S1 floats
    unsigned short* wb = (unsigned short*)(ws + 8 * S1);
    unsigned short* Wqb   = wb;                 // 65536
    unsigned short* Wkb   = wb + 65536;
    unsigned short* Wvb   = wb + 131072;
    unsigned short* Wob   = wb + 196608;
    unsigned short* soWb  = wb + 262144;        // 65536
    unsigned short* awWb  = wb + 327680;        // 32768
    unsigned short* gateWb= wb + 360448;        // 262144
    unsigned short* l1Wb  = wb + 622592;        // 262144
    unsigned short* l2Wb  = wb + 884736;        // 262144

    CvtArgs ca;
    ca.src[0] = Wq;   ca.dst[0] = Wqb;    ca.n[0] = 65536;
    ca.src[1] = Wk;   ca.dst[1] = Wkb;    ca.n[1] = 65536;
    ca.src[2] = Wv;   ca.dst[2] = Wvb;    ca.n[2] = 65536;
    ca.src[3] = Wo;   ca.dst[3] = Wob;    ca.n[3] = 65536;
    ca.src[4] = so_W; ca.dst[4] = soWb;   ca.n[4] = 65536;
    ca.src[5] = aw_W; ca.dst[5] = awWb;   ca.n[5] = 32768;
    ca.src[6] = gate_W; ca.dst[6] = gateWb; ca.n[6] = 262144;
    ca.src[7] = l1_W; ca.dst[7] = l1Wb;   ca.n[7] = 262144;
    ca.src[8] = l2_W; ca.dst[8] = l2Wb;   ca.n[8] = 262144;
    cvt_weights<<<dim3(256, 9), dim3(256), 0, stream>>>(ca);

    const dim3 blk(256);
    const int MT = NQ / 64;  // 150
    // --- self attention ---
    gemm_mfma<1,0,0><<<dim3(MT, 4), blk, 0, stream>>>(target, qpe, Wqb, bq, b0, NQ, 256, 256);
    gemm_mfma<1,0,0><<<dim3(MT, 4), blk, 0, stream>>>(target, qpe, Wkb, bk, b1, NQ, 256, 256);
    gemm_mfma<0,0,0><<<dim3(MT, 4), blk, 0, stream>>>(target, nullptr, Wvb, bv, b2, NQ, 256, 256);
    attn_kernel<<<BS * NH, dim3(512), 0, stream>>>(b0, b1, b2, b3);
    gemm_mfma<0,0,0><<<dim3(MT, 4), blk, 0, stream>>>(b3, nullptr, Wob, bo, b0, NQ, 256, 256);
    ln_add_kernel<<<NQ, blk, 0, stream>>>(target, b0, g1, be1, b5);
    // --- deformable cross attention ---
    gemm_mfma<1,0,0><<<dim3(MT, 4), blk, 0, stream>>>(b5, qpe, soWb, so_b, b2, NQ, 256, 256);
    gemm_mfma<1,0,0><<<dim3(MT, 2), blk, 0, stream>>>(b5, qpe, awWb, aw_b, b1, NQ, 128, 256);
    prep_kernel<<<NQ, dim3(128), 0, stream>>>(b2, b1, refp, b3, aw_buf);
    deform_kernel<<<NQ, blk, 0, stream>>>(value, b3, aw_buf, b4);
    // --- gated fusion ---
    gemm_mfma<0,1,0><<<dim3(MT, 8), blk, 0, stream>>>(b5, b4, gateWb, gate_b, b6, NQ, 512, 512);
    gate_ln_kernel<<<NQ, blk, 0, stream>>>(b6, b5, b4, g2, be2, b2);
    // --- FFN ---
    gemm_mfma<0,0,1><<<dim3(MT, 16), blk, 0, stream>>>(b2, nullptr, l1Wb, l1_b, b3, NQ, 1024, 256);
    gemm_mfma<0,0,0><<<dim3(MT, 4), blk, 0, stream>>>(b3, nullptr, l2Wb, l2_b, b0, NQ, 256, 1024);
    ln_final_kernel<<<NQ, blk, 0, stream>>>(b2, b0, g3, be3, (float*)d_out);
}